// Round 1
// baseline (180.059 us; speedup 1.0000x reference)
//
#include <hip/hip_runtime.h>
#include <stdint.h>

#define TT 4096
#define HIDD 1024

typedef __attribute__((ext_vector_type(4))) float f32x4;
typedef __attribute__((ext_vector_type(8))) short s16x8;

static constexpr float kScale = 0.125f;   // 1/sqrt(64)
static constexpr float kEps = 1e-6f;

// ---- workspace layout (bytes) ----
static constexpr size_t OFF_HS   = 0;          // bf16 hs swz   [4096][1024]  8 MB
static constexpr size_t OFF_WQKV = 8388608;    // bf16 WqkvT swz [1536][1024] 3 MB
static constexpr size_t OFF_WO   = 11534336;   // bf16 WoT swz  [1024][1024]  2 MB
static constexpr size_t OFF_QKV  = 13631488;   // f32 qkv       [4096][1536] 24 MB
static constexpr size_t OFF_Q    = 0;          // bf16 q  [16][4096][64] (reuse HS)
static constexpr size_t OFF_K    = 8388608;    // bf16 k swz [4][4096][64] (reuse WQKV)
static constexpr size_t OFF_VT   = 38797312;   // bf16 vT swz [4][64][4096] 2 MB
static constexpr size_t OFF_O    = 13631488;   // bf16 attn-out swz [4096][1024] (reuse QKV)

__device__ __forceinline__ unsigned int pk_bf16(float a, float b) {
  union { float f; unsigned int u; } x, y;
  x.f = a; y.f = b;
  unsigned int lo = (x.u + 0x7fffu + ((x.u >> 16) & 1u)) >> 16;
  unsigned int hi = (y.u + 0x7fffu + ((y.u >> 16) & 1u)) >> 16;
  return (lo & 0xffffu) | (hi << 16);
}
__device__ __forceinline__ unsigned short bf16_1(float a) {
  union { float f; unsigned int u; } x; x.f = a;
  return (unsigned short)((x.u + 0x7fffu + ((x.u >> 16) & 1u)) >> 16);
}
__device__ __forceinline__ void gload16(const void* g, void* l) {
  __builtin_amdgcn_global_load_lds(
      (const __attribute__((address_space(1))) unsigned int*)g,
      (__attribute__((address_space(3))) unsigned int*)l, 16, 0, 0);
}

// hs fp32 [T][1024] -> bf16 swizzled (16B chunk index XORed by row&7 within 64-elem groups)
__global__ void k_convert_hs(const float* __restrict__ hs, unsigned short* __restrict__ out) {
  int idx = blockIdx.x * 256 + threadIdx.x;  // T*128
  int t = idx >> 7, kc = idx & 127;
  const float4* src = (const float4*)(hs + (size_t)t * HIDD + kc * 8);
  float4 a = src[0], b = src[1];
  int kcs = (kc & ~7) | ((kc & 7) ^ (t & 7));
  uint4 w;
  w.x = pk_bf16(a.x, a.y); w.y = pk_bf16(a.z, a.w);
  w.z = pk_bf16(b.x, b.y); w.w = pk_bf16(b.z, b.w);
  *(uint4*)(out + (size_t)t * HIDD + kcs * 8) = w;
}

// W fp32 [1024][ncols] -> bf16 W^T [ncols][1024] swizzled by n&7
__global__ void k_convert_w(const float* __restrict__ W, unsigned short* __restrict__ outT, int ncols) {
  int idx = blockIdx.x * 256 + threadIdx.x;  // ncols*128
  int kc = idx / ncols, n = idx % ncols;
  float v[8];
#pragma unroll
  for (int e = 0; e < 8; ++e) v[e] = W[(size_t)(kc * 8 + e) * ncols + n];
  int kcs = (kc & ~7) | ((kc & 7) ^ (n & 7));
  uint4 w;
  w.x = pk_bf16(v[0], v[1]); w.y = pk_bf16(v[2], v[3]);
  w.z = pk_bf16(v[4], v[5]); w.w = pk_bf16(v[6], v[7]);
  *(uint4*)(outT + (size_t)n * HIDD + kcs * 8) = w;
}

// C[M][N] = A[M][K] * Bt[N][K]^T ; A,Bt bf16 chunk-swizzled; C fp32.
// 128x128 tile, BK=64, 4 waves (2x2), 16x16x32 MFMA.
__global__ __launch_bounds__(256) void k_gemm(const unsigned short* __restrict__ A,
                                              const unsigned short* __restrict__ Bt,
                                              float* __restrict__ C, int M, int N, int K) {
  __shared__ __attribute__((aligned(16))) unsigned short As[128 * 64];
  __shared__ __attribute__((aligned(16))) unsigned short Bs[128 * 64];
  const int tid = threadIdx.x;
  const int m0 = blockIdx.y * 128, n0 = blockIdx.x * 128;
  const int wid = tid >> 6, lane = tid & 63;
  const int g = lane >> 4, qi = lane & 15;
  const int wr = wid >> 1, wc = wid & 1;
  const int srow = tid >> 3, schk = tid & 7;
  f32x4 acc[4][4] = {};
  for (int k0 = 0; k0 < K; k0 += 64) {
    __syncthreads();
#pragma unroll
    for (int j = 0; j < 4; ++j) {
      int ra = j * 32 + srow;
      gload16(A + (size_t)(m0 + ra) * K + k0 + schk * 8,
              (char*)As + j * 4096 + (wid << 10));
      gload16(Bt + (size_t)(n0 + ra) * K + k0 + schk * 8,
              (char*)Bs + j * 4096 + (wid << 10));
    }
    __syncthreads();
#pragma unroll
    for (int kh = 0; kh < 2; ++kh) {
      s16x8 af[4], bq[4];
#pragma unroll
      for (int i = 0; i < 4; ++i) {
        int rA = wr * 64 + i * 16 + qi;
        af[i] = *(const s16x8*)((const char*)As + rA * 128 + ((((kh << 2) | g) ^ (rA & 7)) << 4));
        int rB = wc * 64 + i * 16 + qi;
        bq[i] = *(const s16x8*)((const char*)Bs + rB * 128 + ((((kh << 2) | g) ^ (rB & 7)) << 4));
      }
#pragma unroll
      for (int i = 0; i < 4; ++i)
#pragma unroll
        for (int jn = 0; jn < 4; ++jn)
          acc[i][jn] = __builtin_amdgcn_mfma_f32_16x16x32_bf16(af[i], bq[jn], acc[i][jn], 0, 0, 0);
    }
  }
#pragma unroll
  for (int i = 0; i < 4; ++i)
#pragma unroll
    for (int jn = 0; jn < 4; ++jn) {
      int row = m0 + wr * 64 + i * 16 + g * 4;
      int col = n0 + wc * 64 + jn * 16 + qi;
#pragma unroll
      for (int r = 0; r < 4; ++r)
        C[(size_t)(row + r) * N + col] = acc[i][jn][r];
    }
}

// RMSNorm + RoPE for q (slots 0..15) and k (slots 16..19). One wave per (t,slot).
__global__ void k_prep(const float* __restrict__ qkv, const float* __restrict__ cosb,
                       const float* __restrict__ sinb, const float* __restrict__ qw,
                       const float* __restrict__ kw, unsigned short* __restrict__ qo,
                       unsigned short* __restrict__ ko) {
  int rowid = blockIdx.x * 4 + (threadIdx.x >> 6);
  int lane = threadIdx.x & 63;
  int t = rowid / 20, slot = rowid % 20;
  float x = qkv[(size_t)t * 1536 + slot * 64 + lane];
  float ss = x * x;
#pragma unroll
  for (int off = 32; off; off >>= 1) ss += __shfl_xor(ss, off);
  float n = x * rsqrtf(ss * (1.0f / 64.0f) + kEps);
  n *= (slot < 16) ? qw[lane] : kw[lane];
  float c = cosb[t * 32 + (lane & 31)];
  float s = sinb[t * 32 + (lane & 31)];
  float other = __shfl_xor(n, 32);
  float r = (lane < 32) ? (n * c - other * s) : (other * s + n * c);
  unsigned short b = bf16_1(r);
  if (slot < 16) {
    qo[((size_t)slot * TT + t) * 64 + lane] = b;   // linear [h][t][d]
  } else {
    int hv = slot - 16;
    int d = (((lane >> 3) ^ (t & 7)) << 3) | (lane & 7);  // swizzle chunks by t&7
    ko[((size_t)hv * TT + t) * 64 + d] = b;
  }
}

// v: qkv fp32 [t][1280+hv*64+d] -> bf16 vT [hv][d][t], t-chunks swizzled by d&7
__global__ void k_vT(const float* __restrict__ qkv, unsigned short* __restrict__ vt) {
  __shared__ float tile[64][65];
  int t0 = blockIdx.x * 64, hv = blockIdx.y, tid = threadIdx.x;
  int cc = tid & 63, rr0 = tid >> 6;
#pragma unroll
  for (int i = 0; i < 16; ++i) {
    int r = rr0 * 16 + i;
    tile[r][cc] = qkv[(size_t)(t0 + r) * 1536 + 1280 + hv * 64 + cc];
  }
  __syncthreads();
#pragma unroll
  for (int jj = 0; jj < 2; ++jj) {
    int idx = jj * 256 + tid;
    int d = idx >> 3, tc = idx & 7;
    uint4 w;
    w.x = pk_bf16(tile[tc * 8 + 0][d], tile[tc * 8 + 1][d]);
    w.y = pk_bf16(tile[tc * 8 + 2][d], tile[tc * 8 + 3][d]);
    w.z = pk_bf16(tile[tc * 8 + 4][d], tile[tc * 8 + 5][d]);
    w.w = pk_bf16(tile[tc * 8 + 6][d], tile[tc * 8 + 7][d]);
    int tcs = tc ^ (d & 7);
    *(uint4*)(vt + ((size_t)hv * 64 + d) * TT + t0 + tcs * 8) = w;
  }
}

// Flash attention, causal GQA. Swapped QK^T (mfma(K,Q) -> S^T), online softmax,
// P via wave-private swizzled LDS. Each block: q-tiles x and 63-x (uniform work).
__global__ __launch_bounds__(256) void k_attn(const unsigned short* __restrict__ q,
                                              const unsigned short* __restrict__ kk,
                                              const unsigned short* __restrict__ vt,
                                              unsigned short* __restrict__ o) {
  __shared__ __attribute__((aligned(16))) unsigned short Kl[64 * 64];
  __shared__ __attribute__((aligned(16))) unsigned short Vl[64 * 64];
  __shared__ __attribute__((aligned(16))) unsigned short Pl[4][16 * 64];
  const int tid = threadIdx.x;
  const int h = blockIdx.y, hv = h >> 2;
  const int w = tid >> 6, lane = tid & 63, g = lane >> 4, qi = lane & 15;
  const int srow = tid >> 3, schk = tid & 7;
  char* pb = (char*)&Pl[w][0];
  for (int phase = 0; phase < 2; ++phase) {
    const int qt = phase ? (63 - (int)blockIdx.x) : (int)blockIdx.x;
    const int qg = qt * 64 + w * 16 + qi;
    s16x8 qf[2];
#pragma unroll
    for (int kh = 0; kh < 2; ++kh)
      qf[kh] = *(const s16x8*)(q + ((size_t)h * TT + qg) * 64 + kh * 32 + g * 8);
    f32x4 acc[4] = {};
    float m_run = -1e30f, l_run = 0.0f;
    for (int s = 0; s <= qt; ++s) {
      const int kv0 = s * 64;
      __syncthreads();
#pragma unroll
      for (int j = 0; j < 2; ++j) {
        int r = j * 32 + srow;
        gload16(kk + ((size_t)hv * TT + kv0 + r) * 64 + schk * 8,
                (char*)Kl + j * 4096 + (w << 10));
        gload16(vt + ((size_t)hv * 64 + r) * TT + kv0 + schk * 8,
                (char*)Vl + j * 4096 + (w << 10));
      }
      __syncthreads();
      f32x4 sacc[4] = {};
#pragma unroll
      for (int kh = 0; kh < 2; ++kh)
#pragma unroll
        for (int cf = 0; cf < 4; ++cf) {
          int row = cf * 16 + qi;
          s16x8 kf = *(const s16x8*)((const char*)Kl + row * 128 + ((((kh << 2) | g) ^ (row & 7)) << 4));
          sacc[cf] = __builtin_amdgcn_mfma_f32_16x16x32_bf16(kf, qf[kh], sacc[cf], 0, 0, 0);
        }
      // per-lane: q-row = qi (fixed), kv = kv0 + cf*16 + g*4 + r
      float p[16];
      float mt = -1e30f;
      const bool diag = (s == qt);
#pragma unroll
      for (int cf = 0; cf < 4; ++cf)
#pragma unroll
        for (int r = 0; r < 4; ++r) {
          float v = sacc[cf][r] * kScale;
          if (diag && (kv0 + cf * 16 + g * 4 + r) > qg) v = -1e30f;
          p[cf * 4 + r] = v;
          mt = fmaxf(mt, v);
        }
      mt = fmaxf(mt, __shfl_xor(mt, 16));
      mt = fmaxf(mt, __shfl_xor(mt, 32));
      float m_new = fmaxf(m_run, mt);
      float alpha = __expf(m_run - m_new);
      float lsum = 0.0f;
#pragma unroll
      for (int i = 0; i < 16; ++i) { p[i] = __expf(p[i] - m_new); lsum += p[i]; }
      lsum += __shfl_xor(lsum, 16);
      lsum += __shfl_xor(lsum, 32);
      l_run = l_run * alpha + lsum;
      m_run = m_new;
#pragma unroll
      for (int cf = 0; cf < 4; ++cf) acc[cf] *= alpha;
      // P^T stored as [q][kv] (bf16, swizzled by q&7)
#pragma unroll
      for (int cf = 0; cf < 4; ++cf) {
        int chunk = cf * 2 + (g >> 1);
        int base = qi * 128 + ((chunk ^ (qi & 7)) << 4) + ((g & 1) << 3);
        *(unsigned int*)(pb + base) = pk_bf16(p[cf * 4 + 0], p[cf * 4 + 1]);
        *(unsigned int*)(pb + base + 4) = pk_bf16(p[cf * 4 + 2], p[cf * 4 + 3]);
      }
#pragma unroll
      for (int kh = 0; kh < 2; ++kh) {
        s16x8 pf = *(const s16x8*)(pb + qi * 128 + ((((kh << 2) | g) ^ (qi & 7)) << 4));
#pragma unroll
        for (int cf = 0; cf < 4; ++cf) {
          int row = cf * 16 + qi;
          s16x8 vf = *(const s16x8*)((const char*)Vl + row * 128 + ((((kh << 2) | g) ^ (row & 7)) << 4));
          acc[cf] = __builtin_amdgcn_mfma_f32_16x16x32_bf16(vf, pf, acc[cf], 0, 0, 0);
        }
      }
    }
    float inv = 1.0f / l_run;
#pragma unroll
    for (int cf = 0; cf < 4; ++cf) {
      int col = h * 64 + cf * 16 + g * 4;
      int chunk = col >> 3;
      int chs = (chunk & ~7) | ((chunk & 7) ^ (qg & 7));
      char* ob = (char*)o + (size_t)qg * 2048 + (chs << 4) + ((g & 1) << 3);
      *(unsigned int*)ob = pk_bf16(acc[cf][0] * inv, acc[cf][1] * inv);
      *(unsigned int*)(ob + 4) = pk_bf16(acc[cf][2] * inv, acc[cf][3] * inv);
    }
  }
}

extern "C" void kernel_launch(void* const* d_in, const int* in_sizes, int n_in,
                              void* d_out, int out_size, void* d_ws, size_t ws_size,
                              hipStream_t stream) {
  const float* hs   = (const float*)d_in[0];
  const float* cosb = (const float*)d_in[1];
  const float* sinb = (const float*)d_in[2];
  const float* Wq   = (const float*)d_in[3];
  const float* Wk   = (const float*)d_in[4];
  const float* Wv   = (const float*)d_in[5];
  const float* Wo   = (const float*)d_in[6];
  const float* qw   = (const float*)d_in[7];
  const float* kw   = (const float*)d_in[8];
  char* ws = (char*)d_ws;
  unsigned short* hs_swz = (unsigned short*)(ws + OFF_HS);
  unsigned short* wqkv   = (unsigned short*)(ws + OFF_WQKV);
  unsigned short* wo_t   = (unsigned short*)(ws + OFF_WO);
  float*          qkv    = (float*)(ws + OFF_QKV);
  unsigned short* qbf    = (unsigned short*)(ws + OFF_Q);
  unsigned short* kbf    = (unsigned short*)(ws + OFF_K);
  unsigned short* vtb    = (unsigned short*)(ws + OFF_VT);
  unsigned short* obf    = (unsigned short*)(ws + OFF_O);

  k_convert_hs<<<2048, 256, 0, stream>>>(hs, hs_swz);
  k_convert_w<<<512, 256, 0, stream>>>(Wq, wqkv, 1024);
  k_convert_w<<<128, 256, 0, stream>>>(Wk, wqkv + 1024 * 1024, 256);
  k_convert_w<<<128, 256, 0, stream>>>(Wv, wqkv + 1280 * 1024, 256);
  k_convert_w<<<512, 256, 0, stream>>>(Wo, wo_t, 1024);
  k_gemm<<<dim3(12, 32), 256, 0, stream>>>(hs_swz, wqkv, qkv, 4096, 1536, 1024);
  k_prep<<<20480, 256, 0, stream>>>(qkv, cosb, sinb, qw, kw, qbf, kbf);
  k_vT<<<dim3(64, 4), 256, 0, stream>>>(qkv, vtb);
  k_attn<<<dim3(32, 16), 256, 0, stream>>>(qbf, kbf, vtb, obf);
  k_gemm<<<dim3(8, 32), 256, 0, stream>>>(obf, wo_t, (float*)d_out, 4096, 1024, 1024);
}